// Round 2
// baseline (981.489 us; speedup 1.0000x reference)
//
#include <hip/hip_runtime.h>
#include <math.h>

#define B_  64
#define N_  1024
#define H_  64
#define IN_ 512
#define G4  256   // 4*H

// ---------------------------------------------------------------------------
// Kernel A (UNCHANGED this round): xg[m][g] = x_row(m) . W_ih[g] + b_ih + b_hh
// ---------------------------------------------------------------------------
__global__ __launch_bounds__(256) void gemm_xg_kernel(
    const float* __restrict__ x,
    const float* __restrict__ Wih,
    const float* __restrict__ bih,
    const float* __restrict__ bhh,
    float* __restrict__ xg)
{
    __shared__ float As[32][68];   // [k][m_local]
    __shared__ float Bs[32][68];   // [k][g_local]

    const int tid = threadIdx.x;
    const int g0  = blockIdx.x * 64;
    const int m0  = blockIdx.y * 64;

    const int tx = tid & 15;
    const int ty = tid >> 4;

    const int arow = tid >> 3;
    const int ak4  = tid & 7;
    const int brow = tid >> 2;
    const int bk4  = tid & 3;

    float acc[4][4] = {{0.f}};

    for (int k0 = 0; k0 < IN_; k0 += 32) {
        #pragma unroll
        for (int half = 0; half < 2; ++half) {
            const int ml = arow + half * 32;
            const int m  = m0 + ml;
            const int bb = m & 63;
            const int nn = m >> 6;
            const float4 v = *(const float4*)&x[((size_t)(bb * N_ + nn)) * IN_ + k0 + ak4 * 4];
            As[ak4 * 4 + 0][ml] = v.x;
            As[ak4 * 4 + 1][ml] = v.y;
            As[ak4 * 4 + 2][ml] = v.z;
            As[ak4 * 4 + 3][ml] = v.w;
        }
        #pragma unroll
        for (int half = 0; half < 2; ++half) {
            const int kq = bk4 + half * 4;
            const float4 v = *(const float4*)&Wih[(size_t)(g0 + brow) * IN_ + k0 + kq * 4];
            Bs[kq * 4 + 0][brow] = v.x;
            Bs[kq * 4 + 1][brow] = v.y;
            Bs[kq * 4 + 2][brow] = v.z;
            Bs[kq * 4 + 3][brow] = v.w;
        }
        __syncthreads();

        #pragma unroll
        for (int k = 0; k < 32; ++k) {
            const float4 av = *(const float4*)&As[k][ty * 4];
            const float4 bv = *(const float4*)&Bs[k][tx * 4];
            const float ar[4] = {av.x, av.y, av.z, av.w};
            const float br[4] = {bv.x, bv.y, bv.z, bv.w};
            #pragma unroll
            for (int i = 0; i < 4; ++i)
                #pragma unroll
                for (int j = 0; j < 4; ++j)
                    acc[i][j] = fmaf(ar[i], br[j], acc[i][j]);
        }
        __syncthreads();
    }

    float bias[4];
    #pragma unroll
    for (int j = 0; j < 4; ++j)
        bias[j] = bih[g0 + tx * 4 + j] + bhh[g0 + tx * 4 + j];

    #pragma unroll
    for (int i = 0; i < 4; ++i) {
        const int m = m0 + ty * 4 + i;
        float4 o;
        o.x = acc[i][0] + bias[0];
        o.y = acc[i][1] + bias[1];
        o.z = acc[i][2] + bias[2];
        o.w = acc[i][3] + bias[3];
        *(float4*)&xg[(size_t)m * G4 + g0 + tx * 4] = o;
    }
}

// ---------------------------------------------------------------------------
// Kernel B: recurrent scan, v3.
//   256 threads (4 waves), one block per batch row.
//   Lane layout: wave w (0..3), lane ln (0..63).
//     cell  = w*16 + (ln>>2)   (16 cells per wave, 64 total)
//     gate  = ln&3             (0=i, 1=f, 2=g, 3=o)
//     W row = gate*64 + cell
//   Each lane computes the FULL 64-long dot for its gate:
//     - 16 float4 = 64 VGPRs of W_hh, FORCED register-resident via an opaque
//       asm keep-alive (R0/R1 evidence: VGPR_Count 48/36 => compiler was
//       re-loading the weights from global memory inside every serial step).
//     - 4 independent accumulators -> 16-deep dependent chains.
//   Gate gather is INTRA-WAVE: the 4 gates of a cell live in 4 adjacent
//   lanes -> 4 ds_bpermute (__shfl), no LDS, no barrier. All 4 group lanes
//   redundantly compute the cell update (identical values, no divergence).
//   Cross-wave traffic is ONLY h (64 floats): double-buffered h_sh,
//   ONE barrier per step.
//   Branchless activation: v = A + B*rcp(1+exp(C*acc)), per-lane constants
//   (A,B,C) = (1,-2,2) for tanh-gate, (0,1,-1) for sigmoid-gates.
// ---------------------------------------------------------------------------
__device__ __forceinline__ float fast_rcp(float x) {
    return __builtin_amdgcn_rcpf(x);
}

__global__ __launch_bounds__(256) void lstm_scan_kernel(
    const float* __restrict__ xg,    // [N][B][256]
    const float* __restrict__ Whh,   // [256][64]
    float* __restrict__ out)         // [B][N][64]
{
    const int t    = threadIdx.x;      // 0..255
    const int bb   = blockIdx.x;       // batch row
    const int w    = t >> 6;           // wave 0..3
    const int ln   = t & 63;           // lane in wave
    const int cell = (w << 4) | (ln >> 2);   // 0..63
    const int gidx = ln & 3;                 // 0..3
    const int grow = (gidx << 6) | cell;     // W_hh / xg gate-row index

    __shared__ float h_sh[2][64];

    // Full W_hh row -> 16 float4 = 64 VGPRs.
    float4 w4[16];
    {
        const float* wrow = &Whh[(size_t)grow * H_];
        #pragma unroll
        for (int q = 0; q < 16; ++q)
            w4[q] = *(const float4*)&wrow[q * 4];
    }
    // Opaque redefinition: compiler cannot rematerialize the loads, so the
    // weights MUST stay live in registers across the 1024-step loop.
    #pragma unroll
    for (int q = 0; q < 16; ++q)
        asm volatile("" : "+v"(w4[q].x), "+v"(w4[q].y), "+v"(w4[q].z), "+v"(w4[q].w));

    // branchless activation constants
    const float Ac = (gidx == 2) ? 1.f : 0.f;
    const float Bc = (gidx == 2) ? -2.f : 1.f;
    const float Cc = (gidx == 2) ? 2.f : -1.f;

    const int baseln = t & 60;         // first lane of this cell's 4-lane group

    float c = 0.f;                     // cell state (replicated in 4 group lanes)
    if (t < 64) { h_sh[0][t] = 0.f; }
    __syncthreads();

    int cur = 0;
    float xg_cur = xg[(size_t)bb * G4 + grow];   // n = 0

    for (int n = 0; n < N_; ++n) {
        // prefetch next step's xg (off the critical path)
        const int n1 = (n + 1 < N_) ? (n + 1) : (N_ - 1);
        const float xg_next = xg[((size_t)n1 * B_ + bb) * G4 + grow];

        // --- full dot: W_hh[grow] . h, 4-way ILP, h via LDS broadcast ---
        float a0 = 0.f, a1 = 0.f, a2 = 0.f, a3 = 0.f;
        #pragma unroll
        for (int q = 0; q < 16; ++q) {
            const float4 hv = *(const float4*)&h_sh[cur][q * 4];
            a0 = fmaf(w4[q].x, hv.x, a0);
            a1 = fmaf(w4[q].y, hv.y, a1);
            a2 = fmaf(w4[q].z, hv.z, a2);
            a3 = fmaf(w4[q].w, hv.w, a3);
        }
        const float acc = ((a0 + a1) + (a2 + a3)) + xg_cur;

        // --- branchless activation ---
        const float v = fmaf(Bc, fast_rcp(1.f + __expf(Cc * acc)), Ac);

        // --- intra-wave gate gather (no LDS, no barrier) ---
        const float vi = __shfl(v, baseln + 0);
        const float vf = __shfl(v, baseln + 1);
        const float vg = __shfl(v, baseln + 2);
        const float vo = __shfl(v, baseln + 3);

        // --- cell update (redundant in the 4 group lanes, identical) ---
        c = fmaf(vf, c, vi * vg);
        const float th = fmaf(-2.f, fast_rcp(1.f + __expf(2.f * c)), 1.f); // tanh(c)
        const float h  = vo * th;

        if (gidx == 0) {
            h_sh[cur ^ 1][cell] = h;
            out[((size_t)bb * N_ + n) * H_ + cell] = h;
        }
        __syncthreads();               // the ONLY barrier per step

        cur ^= 1;
        xg_cur = xg_next;
    }
}

extern "C" void kernel_launch(void* const* d_in, const int* in_sizes, int n_in,
                              void* d_out, int out_size, void* d_ws, size_t ws_size,
                              hipStream_t stream)
{
    const float* x   = (const float*)d_in[0];
    const float* Wih = (const float*)d_in[1];
    const float* Whh = (const float*)d_in[2];
    const float* bih = (const float*)d_in[3];
    const float* bhh = (const float*)d_in[4];
    float* out = (float*)d_out;
    float* xg  = (float*)d_ws;   // 65536 * 256 * 4 B = 64 MiB scratch

    dim3 ggrid(4, 1024);   // (g-tiles, m-tiles)
    gemm_xg_kernel<<<ggrid, 256, 0, stream>>>(x, Wih, bih, bhh, xg);
    lstm_scan_kernel<<<64, 256, 0, stream>>>(xg, Whh, out);
}

// Round 3
// 786.033 us; speedup vs baseline: 1.2487x; 1.2487x over previous
//
#include <hip/hip_runtime.h>
#include <math.h>

#define B_  64
#define N_  1024
#define H_  64
#define IN_ 512
#define G4  256   // 4*H

// ---------------------------------------------------------------------------
// Kernel A (UNCHANGED this round): xg[m][g] = x_row(m) . W_ih[g] + b_ih + b_hh
// ---------------------------------------------------------------------------
__global__ __launch_bounds__(256) void gemm_xg_kernel(
    const float* __restrict__ x,
    const float* __restrict__ Wih,
    const float* __restrict__ bih,
    const float* __restrict__ bhh,
    float* __restrict__ xg)
{
    __shared__ float As[32][68];   // [k][m_local]
    __shared__ float Bs[32][68];   // [k][g_local]

    const int tid = threadIdx.x;
    const int g0  = blockIdx.x * 64;
    const int m0  = blockIdx.y * 64;

    const int tx = tid & 15;
    const int ty = tid >> 4;

    const int arow = tid >> 3;
    const int ak4  = tid & 7;
    const int brow = tid >> 2;
    const int bk4  = tid & 3;

    float acc[4][4] = {{0.f}};

    for (int k0 = 0; k0 < IN_; k0 += 32) {
        #pragma unroll
        for (int half = 0; half < 2; ++half) {
            const int ml = arow + half * 32;
            const int m  = m0 + ml;
            const int bb = m & 63;
            const int nn = m >> 6;
            const float4 v = *(const float4*)&x[((size_t)(bb * N_ + nn)) * IN_ + k0 + ak4 * 4];
            As[ak4 * 4 + 0][ml] = v.x;
            As[ak4 * 4 + 1][ml] = v.y;
            As[ak4 * 4 + 2][ml] = v.z;
            As[ak4 * 4 + 3][ml] = v.w;
        }
        #pragma unroll
        for (int half = 0; half < 2; ++half) {
            const int kq = bk4 + half * 4;
            const float4 v = *(const float4*)&Wih[(size_t)(g0 + brow) * IN_ + k0 + kq * 4];
            Bs[kq * 4 + 0][brow] = v.x;
            Bs[kq * 4 + 1][brow] = v.y;
            Bs[kq * 4 + 2][brow] = v.z;
            Bs[kq * 4 + 3][brow] = v.w;
        }
        __syncthreads();

        #pragma unroll
        for (int k = 0; k < 32; ++k) {
            const float4 av = *(const float4*)&As[k][ty * 4];
            const float4 bv = *(const float4*)&Bs[k][tx * 4];
            const float ar[4] = {av.x, av.y, av.z, av.w};
            const float br[4] = {bv.x, bv.y, bv.z, bv.w};
            #pragma unroll
            for (int i = 0; i < 4; ++i)
                #pragma unroll
                for (int j = 0; j < 4; ++j)
                    acc[i][j] = fmaf(ar[i], br[j], acc[i][j]);
        }
        __syncthreads();
    }

    float bias[4];
    #pragma unroll
    for (int j = 0; j < 4; ++j)
        bias[j] = bih[g0 + tx * 4 + j] + bhh[g0 + tx * 4 + j];

    #pragma unroll
    for (int i = 0; i < 4; ++i) {
        const int m = m0 + ty * 4 + i;
        float4 o;
        o.x = acc[i][0] + bias[0];
        o.y = acc[i][1] + bias[1];
        o.z = acc[i][2] + bias[2];
        o.w = acc[i][3] + bias[3];
        *(float4*)&xg[(size_t)m * G4 + g0 + tx * 4] = o;
    }
}

// ---------------------------------------------------------------------------
// Kernel B: recurrent scan, v4.
//   512 threads (8 waves), one block per batch row.
//   8 lanes per cell: half = ln&1, gate = (ln>>1)&3, cell = w*8 + (ln>>3).
//   Each lane computes HALF of one gate's 64-dot (8 float4 = 32 weight VGPRs,
//   short 8-deep chains, 4-way ILP). Half-combine AND 4-gate gather are
//   intra-wave ds_swizzle -> the gate LDS round-trip + its barrier are gone.
//   Cross-wave traffic is only h (64 floats): double-buffered, ONE barrier.
//
//   KEY CHANGE vs R1/R2: 4-deep xg prefetch. R1/R2 counters showed ~half the
//   xg stream misses to HBM (~900 cyc) with only a 1-step-deep prefetch
//   (~500-cyc steps) -> every step stalled on vmcnt for its own xg load.
//   Four named prefetch registers (no runtime-indexed array -> no scratch)
//   give ~3.5 steps (>1300 cyc) of latency budget.
// ---------------------------------------------------------------------------
__device__ __forceinline__ float fast_rcp(float x) {
    return __builtin_amdgcn_rcpf(x);
}

template <int IMM>
__device__ __forceinline__ float dswz(float x) {
    return __int_as_float(__builtin_amdgcn_ds_swizzle(__float_as_int(x), IMM));
}
// BitMode offsets: lane' = ((lane & and) | or) ^ xor   (within 32-lane halves)
#define SWZ_XOR1  0x041F   // xor=1, and=0x1F           : partner half
#define SWZ_G0    0x0018   // and=0x18, or=0            : lane base+0 (gate i)
#define SWZ_G1    0x0058   // and=0x18, or=2            : lane base+2 (gate f)
#define SWZ_G2    0x0098   // and=0x18, or=4            : lane base+4 (gate g)
#define SWZ_G3    0x00D8   // and=0x18, or=6            : lane base+6 (gate o)

__global__ __launch_bounds__(512) void lstm_scan_kernel(
    const float* __restrict__ xg,    // [N][B][256]
    const float* __restrict__ Whh,   // [256][64]
    float* __restrict__ out)         // [B][N][64]
{
    const int t    = threadIdx.x;            // 0..511
    const int bb   = blockIdx.x;             // batch row
    const int w    = t >> 6;                 // wave 0..7
    const int ln   = t & 63;                 // lane in wave
    const int half = ln & 1;                 // half of the 64-dot
    const int gidx = (ln >> 1) & 3;          // 0=i 1=f 2=g 3=o
    const int cell = (w << 3) | (ln >> 3);   // 0..63
    const int grow = (gidx << 6) | cell;     // W_hh / xg row

    __shared__ float h_sh[2][64];

    // Half of W_hh row -> 8 float4 = 32 VGPRs.
    float4 w4[8];
    {
        const float* wrow = &Whh[(size_t)grow * H_ + half * 32];
        #pragma unroll
        for (int q = 0; q < 8; ++q)
            w4[q] = *(const float4*)&wrow[q * 4];
    }
    #pragma unroll
    for (int q = 0; q < 8; ++q)
        asm volatile("" : "+v"(w4[q].x), "+v"(w4[q].y), "+v"(w4[q].z), "+v"(w4[q].w));

    // branchless activation constants: v = Ac + Bc * rcp(1 + exp(Cc*acc))
    const float Ac = (gidx == 2) ? 1.f : 0.f;
    const float Bc = (gidx == 2) ? -2.f : 1.f;
    const float Cc = (gidx == 2) ? 2.f : -1.f;

    float c = 0.f;                     // cell state (replicated in 8 group lanes)
    if (t < 64) h_sh[0][t] = 0.f;
    __syncthreads();

    int cur = 0;
    const size_t xg_base = (size_t)bb * G4 + grow;
    const size_t xg_nstride = (size_t)B_ * G4;

    // 4-deep prefetch pipeline (named registers -> stays in VGPRs)
    float p0 = xg[xg_base + 0 * xg_nstride];
    float p1 = xg[xg_base + 1 * xg_nstride];
    float p2 = xg[xg_base + 2 * xg_nstride];
    float p3 = xg[xg_base + 3 * xg_nstride];

    auto step = [&](int n, float xg_cur) {
        // --- half-dot: W_hh[grow][half*32..+32) . h, 4-way ILP ---
        const float* hb = &h_sh[cur][half * 32];
        float a0 = 0.f, a1 = 0.f, a2 = 0.f, a3 = 0.f;
        #pragma unroll
        for (int q = 0; q < 8; ++q) {
            const float4 hv = *(const float4*)&hb[q * 4];
            a0 = fmaf(w4[q].x, hv.x, a0);
            a1 = fmaf(w4[q].y, hv.y, a1);
            a2 = fmaf(w4[q].z, hv.z, a2);
            a3 = fmaf(w4[q].w, hv.w, a3);
        }
        float acc = (a0 + a1) + (a2 + a3);
        acc += dswz<SWZ_XOR1>(acc);          // combine halves (intra-wave)
        acc += xg_cur;

        // --- branchless activation ---
        const float v = fmaf(Bc, fast_rcp(1.f + __expf(Cc * acc)), Ac);

        // --- intra-wave 4-gate gather (8-lane group broadcast) ---
        const float vi = dswz<SWZ_G0>(v);
        const float vf = dswz<SWZ_G1>(v);
        const float vg = dswz<SWZ_G2>(v);
        const float vo = dswz<SWZ_G3>(v);

        // --- cell update (redundant in the 8 group lanes, identical) ---
        c = fmaf(vf, c, vi * vg);
        const float th = fmaf(-2.f, fast_rcp(1.f + __expf(2.f * c)), 1.f); // tanh(c)
        const float h  = vo * th;

        if ((ln & 7) == 0) {
            h_sh[cur ^ 1][cell] = h;
            out[((size_t)bb * N_ + n) * H_ + cell] = h;
        }
        __syncthreads();                     // the ONLY barrier per step
        cur ^= 1;
    };

    for (int n = 0; n < N_; n += 4) {
        // compute with the oldest prefetch, then refill that slot (+4 ahead)
        step(n + 0, p0);
        p0 = xg[xg_base + (size_t)((n + 4 < N_) ? n + 4 : N_ - 1) * xg_nstride];
        step(n + 1, p1);
        p1 = xg[xg_base + (size_t)((n + 5 < N_) ? n + 5 : N_ - 1) * xg_nstride];
        step(n + 2, p2);
        p2 = xg[xg_base + (size_t)((n + 6 < N_) ? n + 6 : N_ - 1) * xg_nstride];
        step(n + 3, p3);
        p3 = xg[xg_base + (size_t)((n + 7 < N_) ? n + 7 : N_ - 1) * xg_nstride];
    }
}

extern "C" void kernel_launch(void* const* d_in, const int* in_sizes, int n_in,
                              void* d_out, int out_size, void* d_ws, size_t ws_size,
                              hipStream_t stream)
{
    const float* x   = (const float*)d_in[0];
    const float* Wih = (const float*)d_in[1];
    const float* Whh = (const float*)d_in[2];
    const float* bih = (const float*)d_in[3];
    const float* bhh = (const float*)d_in[4];
    float* out = (float*)d_out;
    float* xg  = (float*)d_ws;   // 65536 * 256 * 4 B = 64 MiB scratch

    dim3 ggrid(4, 1024);   // (g-tiles, m-tiles)
    gemm_xg_kernel<<<ggrid, 256, 0, stream>>>(x, Wih, bih, bhh, xg);
    lstm_scan_kernel<<<64, 512, 0, stream>>>(xg, Whh, out);
}

// Round 5
// 712.421 us; speedup vs baseline: 1.3777x; 1.1033x over previous
//
#include <hip/hip_runtime.h>
#include <math.h>

#define B_  64
#define N_  1024
#define H_  64
#define IN_ 512
#define G4  256   // 4*H

// ---------------------------------------------------------------------------
// Kernel A (UNCHANGED this round): xg[m][g] = x_row(m) . W_ih[g] + b_ih + b_hh
// ---------------------------------------------------------------------------
__global__ __launch_bounds__(256) void gemm_xg_kernel(
    const float* __restrict__ x,
    const float* __restrict__ Wih,
    const float* __restrict__ bih,
    const float* __restrict__ bhh,
    float* __restrict__ xg)
{
    __shared__ float As[32][68];   // [k][m_local]
    __shared__ float Bs[32][68];   // [k][g_local]

    const int tid = threadIdx.x;
    const int g0  = blockIdx.x * 64;
    const int m0  = blockIdx.y * 64;

    const int tx = tid & 15;
    const int ty = tid >> 4;

    const int arow = tid >> 3;
    const int ak4  = tid & 7;
    const int brow = tid >> 2;
    const int bk4  = tid & 3;

    float acc[4][4] = {{0.f}};

    for (int k0 = 0; k0 < IN_; k0 += 32) {
        #pragma unroll
        for (int half = 0; half < 2; ++half) {
            const int ml = arow + half * 32;
            const int m  = m0 + ml;
            const int bb = m & 63;
            const int nn = m >> 6;
            const float4 v = *(const float4*)&x[((size_t)(bb * N_ + nn)) * IN_ + k0 + ak4 * 4];
            As[ak4 * 4 + 0][ml] = v.x;
            As[ak4 * 4 + 1][ml] = v.y;
            As[ak4 * 4 + 2][ml] = v.z;
            As[ak4 * 4 + 3][ml] = v.w;
        }
        #pragma unroll
        for (int half = 0; half < 2; ++half) {
            const int kq = bk4 + half * 4;
            const float4 v = *(const float4*)&Wih[(size_t)(g0 + brow) * IN_ + k0 + kq * 4];
            Bs[kq * 4 + 0][brow] = v.x;
            Bs[kq * 4 + 1][brow] = v.y;
            Bs[kq * 4 + 2][brow] = v.z;
            Bs[kq * 4 + 3][brow] = v.w;
        }
        __syncthreads();

        #pragma unroll
        for (int k = 0; k < 32; ++k) {
            const float4 av = *(const float4*)&As[k][ty * 4];
            const float4 bv = *(const float4*)&Bs[k][tx * 4];
            const float ar[4] = {av.x, av.y, av.z, av.w};
            const float br[4] = {bv.x, bv.y, bv.z, bv.w};
            #pragma unroll
            for (int i = 0; i < 4; ++i)
                #pragma unroll
                for (int j = 0; j < 4; ++j)
                    acc[i][j] = fmaf(ar[i], br[j], acc[i][j]);
        }
        __syncthreads();
    }

    float bias[4];
    #pragma unroll
    for (int j = 0; j < 4; ++j)
        bias[j] = bih[g0 + tx * 4 + j] + bhh[g0 + tx * 4 + j];

    #pragma unroll
    for (int i = 0; i < 4; ++i) {
        const int m = m0 + ty * 4 + i;
        float4 o;
        o.x = acc[i][0] + bias[0];
        o.y = acc[i][1] + bias[1];
        o.z = acc[i][2] + bias[2];
        o.w = acc[i][3] + bias[3];
        *(float4*)&xg[(size_t)m * G4 + g0 + tx * 4] = o;
    }
}

// ---------------------------------------------------------------------------
// Kernel B: recurrent scan, v5.1 (= v5 with the double-xg seed bug fixed).
//   512 threads (8 waves), one block per batch row.
//   8 lanes per cell: half = ln&1, gate = (ln>>1)&3, cell = w*8 + (ln>>3).
//   Group-lane positions: 0,1 = i-gate halves; 2,3 = f; 4,5 = g; 6,7 = o.
//
//   All cross-lane traffic on the VALU DPP pipe (~4 cy) instead of the LDS
//   pipe (ds_swizzle, ~100 cy):
//     - half-combine: v_add + quad_perm(1,0,3,2)          [0xB1]
//       BUGFIX vs v5: xg is seeded ONLY in the half-0 lane; v5 seeded both
//       halves and the lane^1 combine then counted xg twice (absmax 0.94).
//     - gate gather + cell update fused into 2 DPP ops:
//         u = (o-lane) ? c : v
//         t = row_shr:4(u)     -> g-lanes get vI, o-lanes get vF
//         w = u*t              -> g-lanes: vG*vI, o-lanes: c*vF
//         s = w + row_shr:2(w) -> o-lanes: c_new = c*vF + vI*vG
//         h = vO * tanh(s)     (v at o-lanes IS vO)
//         c = s                (only o-lanes ever read c next step)
//   Only LDS op on the critical path: h write -> barrier -> h read.
//   Keeps R3's 4-deep xg prefetch (HBM-latency cover, proven +200us).
// ---------------------------------------------------------------------------
__device__ __forceinline__ float fast_rcp(float x) {
    return __builtin_amdgcn_rcpf(x);
}

template <int CTRL>
__device__ __forceinline__ float dppf(float x) {
    return __int_as_float(__builtin_amdgcn_mov_dpp(
        __float_as_int(x), CTRL, 0xF, 0xF, true));
}
#define DPP_QSWAP1 0xB1   // quad_perm(1,0,3,2): lane^1
#define DPP_SHR4   0x114  // dst[i] = src[i-4] (within 16-lane row)
#define DPP_SHR2   0x112  // dst[i] = src[i-2]

__global__ __launch_bounds__(512) void lstm_scan_kernel(
    const float* __restrict__ xg,    // [N][B][256]
    const float* __restrict__ Whh,   // [256][64]
    float* __restrict__ out)         // [B][N][64]
{
    const int t    = threadIdx.x;            // 0..511
    const int bb   = blockIdx.x;             // batch row
    const int w    = t >> 6;                 // wave 0..7
    const int ln   = t & 63;                 // lane in wave
    const int half = ln & 1;                 // half of the 64-dot
    const int gidx = (ln >> 1) & 3;          // 0=i 1=f 2=g 3=o
    const int cell = (w << 3) | (ln >> 3);   // 0..63
    const int grow = (gidx << 6) | cell;     // W_hh / xg row

    __shared__ float h_sh[2][64];

    // Half of W_hh row -> 8 float4 (AGPR-resident is fine on gfx950).
    float4 w4[8];
    {
        const float* wrow = &Whh[(size_t)grow * H_ + half * 32];
        #pragma unroll
        for (int q = 0; q < 8; ++q)
            w4[q] = *(const float4*)&wrow[q * 4];
    }
    #pragma unroll
    for (int q = 0; q < 8; ++q)
        asm volatile("" : "+v"(w4[q].x), "+v"(w4[q].y), "+v"(w4[q].z), "+v"(w4[q].w));

    // branchless activation constants: v = Ac + Bc * rcp(1 + exp(Cc*acc))
    const float Ac = (gidx == 2) ? 1.f : 0.f;
    const float Bc = (gidx == 2) ? -2.f : 1.f;
    const float Cc = (gidx == 2) ? 2.f : -1.f;
    const bool  is_o = (gidx == 3);
    const bool  is_writer = ((ln & 7) == 6);
    const bool  carries_xg = (half == 0);    // BUGFIX: xg enters the combine once

    float c = 0.f;                     // cell state (valid at o-lanes)
    if (t < 64) h_sh[0][t] = 0.f;
    __syncthreads();

    int cur = 0;
    const size_t xg_base = (size_t)bb * G4 + grow;
    const size_t xg_nstride = (size_t)B_ * G4;

    // 4-deep prefetch pipeline (named registers -> stays in VGPRs)
    float p0 = xg[xg_base + 0 * xg_nstride];
    float p1 = xg[xg_base + 1 * xg_nstride];
    float p2 = xg[xg_base + 2 * xg_nstride];
    float p3 = xg[xg_base + 3 * xg_nstride];

    auto step = [&](int n, float xg_cur) {
        // --- half-dot: W_hh[grow][half*32..+32) . h, 8 accs (4-deep chains)
        const float* hb = &h_sh[cur][half * 32];
        float b0 = carries_xg ? xg_cur : 0.f;
        float b1 = 0.f, b2 = 0.f, b3 = 0.f;
        float b4 = 0.f, b5 = 0.f, b6 = 0.f, b7 = 0.f;
        #pragma unroll
        for (int q = 0; q < 8; q += 2) {
            const float4 h0 = *(const float4*)&hb[q * 4];
            const float4 h1 = *(const float4*)&hb[q * 4 + 4];
            b0 = fmaf(w4[q].x,     h0.x, b0);
            b1 = fmaf(w4[q].y,     h0.y, b1);
            b2 = fmaf(w4[q].z,     h0.z, b2);
            b3 = fmaf(w4[q].w,     h0.w, b3);
            b4 = fmaf(w4[q + 1].x, h1.x, b4);
            b5 = fmaf(w4[q + 1].y, h1.y, b5);
            b6 = fmaf(w4[q + 1].z, h1.z, b6);
            b7 = fmaf(w4[q + 1].w, h1.w, b7);
        }
        float acc = ((b0 + b4) + (b1 + b5)) + ((b2 + b6) + (b3 + b7));
        acc += dppf<DPP_QSWAP1>(acc);        // + partner half (VALU DPP)

        // --- branchless activation ---
        const float v = fmaf(Bc, fast_rcp(1.f + __expf(Cc * acc)), Ac);

        // --- fused gate-gather + cell update, 2 DPP ops, no LDS pipe ---
        const float u  = is_o ? c : v;
        const float t_ = dppf<DPP_SHR4>(u);  // g-lanes: vI, o-lanes: vF
        const float w_ = u * t_;             // g-lanes: vG*vI, o-lanes: c*vF
        const float s  = w_ + dppf<DPP_SHR2>(w_); // o-lanes: c_new
        const float th = fmaf(-2.f, fast_rcp(1.f + __expf(2.f * s)), 1.f);
        const float h  = v * th;             // o-lanes: vO * tanh(c_new)
        c = s;                               // only o-lanes read c next step

        if (is_writer) {                     // group position 6 (an o-lane)
            h_sh[cur ^ 1][cell] = h;
            out[((size_t)bb * N_ + n) * H_ + cell] = h;
        }
        __syncthreads();                     // the ONLY barrier per step
        cur ^= 1;
    };

    for (int n = 0; n < N_; n += 4) {
        step(n + 0, p0);
        p0 = xg[xg_base + (size_t)((n + 4 < N_) ? n + 4 : N_ - 1) * xg_nstride];
        step(n + 1, p1);
        p1 = xg[xg_base + (size_t)((n + 5 < N_) ? n + 5 : N_ - 1) * xg_nstride];
        step(n + 2, p2);
        p2 = xg[xg_base + (size_t)((n + 6 < N_) ? n + 6 : N_ - 1) * xg_nstride];
        step(n + 3, p3);
        p3 = xg[xg_base + (size_t)((n + 7 < N_) ? n + 7 : N_ - 1) * xg_nstride];
    }
}

extern "C" void kernel_launch(void* const* d_in, const int* in_sizes, int n_in,
                              void* d_out, int out_size, void* d_ws, size_t ws_size,
                              hipStream_t stream)
{
    const float* x   = (const float*)d_in[0];
    const float* Wih = (const float*)d_in[1];
    const float* Whh = (const float*)d_in[2];
    const float* bih = (const float*)d_in[3];
    const float* bhh = (const float*)d_in[4];
    float* out = (float*)d_out;
    float* xg  = (float*)d_ws;   // 65536 * 256 * 4 B = 64 MiB scratch

    dim3 ggrid(4, 1024);   // (g-tiles, m-tiles)
    gemm_xg_kernel<<<ggrid, 256, 0, stream>>>(x, Wih, bih, bhh, xg);
    lstm_scan_kernel<<<64, 512, 0, stream>>>(xg, Whh, out);
}

// Round 6
// 707.489 us; speedup vs baseline: 1.3873x; 1.0070x over previous
//
#include <hip/hip_runtime.h>
#include <math.h>

#define B_  64
#define N_  1024
#define H_  64
#define IN_ 512
#define G4  256   // 4*H

// ---------------------------------------------------------------------------
// Kernel A (UNCHANGED this round): xg[m][g] = x_row(m) . W_ih[g] + b_ih + b_hh
// ---------------------------------------------------------------------------
__global__ __launch_bounds__(256) void gemm_xg_kernel(
    const float* __restrict__ x,
    const float* __restrict__ Wih,
    const float* __restrict__ bih,
    const float* __restrict__ bhh,
    float* __restrict__ xg)
{
    __shared__ float As[32][68];   // [k][m_local]
    __shared__ float Bs[32][68];   // [k][g_local]

    const int tid = threadIdx.x;
    const int g0  = blockIdx.x * 64;
    const int m0  = blockIdx.y * 64;

    const int tx = tid & 15;
    const int ty = tid >> 4;

    const int arow = tid >> 3;
    const int ak4  = tid & 7;
    const int brow = tid >> 2;
    const int bk4  = tid & 3;

    float acc[4][4] = {{0.f}};

    for (int k0 = 0; k0 < IN_; k0 += 32) {
        #pragma unroll
        for (int half = 0; half < 2; ++half) {
            const int ml = arow + half * 32;
            const int m  = m0 + ml;
            const int bb = m & 63;
            const int nn = m >> 6;
            const float4 v = *(const float4*)&x[((size_t)(bb * N_ + nn)) * IN_ + k0 + ak4 * 4];
            As[ak4 * 4 + 0][ml] = v.x;
            As[ak4 * 4 + 1][ml] = v.y;
            As[ak4 * 4 + 2][ml] = v.z;
            As[ak4 * 4 + 3][ml] = v.w;
        }
        #pragma unroll
        for (int half = 0; half < 2; ++half) {
            const int kq = bk4 + half * 4;
            const float4 v = *(const float4*)&Wih[(size_t)(g0 + brow) * IN_ + k0 + kq * 4];
            Bs[kq * 4 + 0][brow] = v.x;
            Bs[kq * 4 + 1][brow] = v.y;
            Bs[kq * 4 + 2][brow] = v.z;
            Bs[kq * 4 + 3][brow] = v.w;
        }
        __syncthreads();

        #pragma unroll
        for (int k = 0; k < 32; ++k) {
            const float4 av = *(const float4*)&As[k][ty * 4];
            const float4 bv = *(const float4*)&Bs[k][tx * 4];
            const float ar[4] = {av.x, av.y, av.z, av.w};
            const float br[4] = {bv.x, bv.y, bv.z, bv.w};
            #pragma unroll
            for (int i = 0; i < 4; ++i)
                #pragma unroll
                for (int j = 0; j < 4; ++j)
                    acc[i][j] = fmaf(ar[i], br[j], acc[i][j]);
        }
        __syncthreads();
    }

    float bias[4];
    #pragma unroll
    for (int j = 0; j < 4; ++j)
        bias[j] = bih[g0 + tx * 4 + j] + bhh[g0 + tx * 4 + j];

    #pragma unroll
    for (int i = 0; i < 4; ++i) {
        const int m = m0 + ty * 4 + i;
        float4 o;
        o.x = acc[i][0] + bias[0];
        o.y = acc[i][1] + bias[1];
        o.z = acc[i][2] + bias[2];
        o.w = acc[i][3] + bias[3];
        *(float4*)&xg[(size_t)m * G4 + g0 + tx * 4] = o;
    }
}

// ---------------------------------------------------------------------------
// Kernel B: recurrent scan, v6 (= v5.1 + lgkmcnt-only barrier).
//   512 threads (8 waves), one block per batch row.
//   8 lanes per cell: half = ln&1, gate = (ln>>1)&3, cell = w*8 + (ln>>3).
//   Group-lane positions: 0,1 = i-gate halves; 2,3 = f; 4,5 = g; 6,7 = o.
//
//   R6 CHANGE: __syncthreads() lowers to `s_waitcnt vmcnt(0) lgkmcnt(0)` +
//   s_barrier, which drained the in-flight xg prefetch loads (L2 ~200cy /
//   HBM ~900cy) and out stores EVERY step -- nullifying the 4-deep prefetch.
//   The only cross-thread traffic through the barrier is LDS (h_sh); xg is
//   read-only and out regions are disjoint. So: raw s_barrier with
//   lgkmcnt(0) only. Prefetch loads/stores now stay in flight across steps
//   (compiler inserts vmcnt(N) at the actual use, 4 steps later).
//
//   Cross-lane traffic all on the VALU DPP pipe:
//     - half-combine: v_add + quad_perm(1,0,3,2); xg seeded in half-0 only.
//     - gate gather + cell update fused into 2 DPP ops:
//         u = (o-lane) ? c : v
//         t = row_shr:4(u)     -> g-lanes get vI, o-lanes get vF
//         w = u*t              -> g-lanes: vG*vI, o-lanes: c*vF
//         s = w + row_shr:2(w) -> o-lanes: c_new = c*vF + vI*vG
//         h = vO * tanh(s);  c = s  (only o-lanes read c next step)
// ---------------------------------------------------------------------------
__device__ __forceinline__ float fast_rcp(float x) {
    return __builtin_amdgcn_rcpf(x);
}

template <int CTRL>
__device__ __forceinline__ float dppf(float x) {
    return __int_as_float(__builtin_amdgcn_mov_dpp(
        __float_as_int(x), CTRL, 0xF, 0xF, true));
}
#define DPP_QSWAP1 0xB1   // quad_perm(1,0,3,2): lane^1
#define DPP_SHR4   0x114  // dst[i] = src[i-4] (within 16-lane row)
#define DPP_SHR2   0x112  // dst[i] = src[i-2]

__global__ __launch_bounds__(512) void lstm_scan_kernel(
    const float* __restrict__ xg,    // [N][B][256]
    const float* __restrict__ Whh,   // [256][64]
    float* __restrict__ out)         // [B][N][64]
{
    const int t    = threadIdx.x;            // 0..511
    const int bb   = blockIdx.x;             // batch row
    const int w    = t >> 6;                 // wave 0..7
    const int ln   = t & 63;                 // lane in wave
    const int half = ln & 1;                 // half of the 64-dot
    const int gidx = (ln >> 1) & 3;          // 0=i 1=f 2=g 3=o
    const int cell = (w << 3) | (ln >> 3);   // 0..63
    const int grow = (gidx << 6) | cell;     // W_hh / xg row

    __shared__ float h_sh[2][64];

    // Half of W_hh row -> 8 float4 (AGPR-resident is fine on gfx950).
    float4 w4[8];
    {
        const float* wrow = &Whh[(size_t)grow * H_ + half * 32];
        #pragma unroll
        for (int q = 0; q < 8; ++q)
            w4[q] = *(const float4*)&wrow[q * 4];
    }
    #pragma unroll
    for (int q = 0; q < 8; ++q)
        asm volatile("" : "+v"(w4[q].x), "+v"(w4[q].y), "+v"(w4[q].z), "+v"(w4[q].w));

    // branchless activation constants: v = Ac + Bc * rcp(1 + exp(Cc*acc))
    const float Ac = (gidx == 2) ? 1.f : 0.f;
    const float Bc = (gidx == 2) ? -2.f : 1.f;
    const float Cc = (gidx == 2) ? 2.f : -1.f;
    const bool  is_o = (gidx == 3);
    const bool  is_writer = ((ln & 7) == 6);
    const bool  carries_xg = (half == 0);    // xg enters the half-combine once

    float c = 0.f;                     // cell state (valid at o-lanes)
    if (t < 64) h_sh[0][t] = 0.f;
    __syncthreads();                   // one-time: full sync is fine here

    int cur = 0;
    const size_t xg_base = (size_t)bb * G4 + grow;
    const size_t xg_nstride = (size_t)B_ * G4;

    // 4-deep prefetch pipeline (named registers -> stays in VGPRs)
    float p0 = xg[xg_base + 0 * xg_nstride];
    float p1 = xg[xg_base + 1 * xg_nstride];
    float p2 = xg[xg_base + 2 * xg_nstride];
    float p3 = xg[xg_base + 3 * xg_nstride];

    auto step = [&](int n, float xg_cur) {
        // --- half-dot: W_hh[grow][half*32..+32) . h, 8 accs (4-deep chains)
        const float* hb = &h_sh[cur][half * 32];
        float b0 = carries_xg ? xg_cur : 0.f;
        float b1 = 0.f, b2 = 0.f, b3 = 0.f;
        float b4 = 0.f, b5 = 0.f, b6 = 0.f, b7 = 0.f;
        #pragma unroll
        for (int q = 0; q < 8; q += 2) {
            const float4 h0 = *(const float4*)&hb[q * 4];
            const float4 h1 = *(const float4*)&hb[q * 4 + 4];
            b0 = fmaf(w4[q].x,     h0.x, b0);
            b1 = fmaf(w4[q].y,     h0.y, b1);
            b2 = fmaf(w4[q].z,     h0.z, b2);
            b3 = fmaf(w4[q].w,     h0.w, b3);
            b4 = fmaf(w4[q + 1].x, h1.x, b4);
            b5 = fmaf(w4[q + 1].y, h1.y, b5);
            b6 = fmaf(w4[q + 1].z, h1.z, b6);
            b7 = fmaf(w4[q + 1].w, h1.w, b7);
        }
        float acc = ((b0 + b4) + (b1 + b5)) + ((b2 + b6) + (b3 + b7));
        acc += dppf<DPP_QSWAP1>(acc);        // + partner half (VALU DPP)

        // --- branchless activation ---
        const float v = fmaf(Bc, fast_rcp(1.f + __expf(Cc * acc)), Ac);

        // --- fused gate-gather + cell update, 2 DPP ops, no LDS pipe ---
        const float u  = is_o ? c : v;
        const float t_ = dppf<DPP_SHR4>(u);  // g-lanes: vI, o-lanes: vF
        const float w_ = u * t_;             // g-lanes: vG*vI, o-lanes: c*vF
        const float s  = w_ + dppf<DPP_SHR2>(w_); // o-lanes: c_new
        const float th = fmaf(-2.f, fast_rcp(1.f + __expf(2.f * s)), 1.f);
        const float h  = v * th;             // o-lanes: vO * tanh(c_new)
        c = s;                               // only o-lanes read c next step

        if (is_writer) {                     // group position 6 (an o-lane)
            h_sh[cur ^ 1][cell] = h;
            out[((size_t)bb * N_ + n) * H_ + cell] = h;
        }

        // --- lgkmcnt-only barrier: do NOT drain vmcnt (prefetch stays live)
        asm volatile("s_waitcnt lgkmcnt(0)" ::: "memory");
        __builtin_amdgcn_s_barrier();
        asm volatile("" ::: "memory");       // pin next step's ds_read after

        cur ^= 1;
    };

    for (int n = 0; n < N_; n += 4) {
        step(n + 0, p0);
        p0 = xg[xg_base + (size_t)((n + 4 < N_) ? n + 4 : N_ - 1) * xg_nstride];
        step(n + 1, p1);
        p1 = xg[xg_base + (size_t)((n + 5 < N_) ? n + 5 : N_ - 1) * xg_nstride];
        step(n + 2, p2);
        p2 = xg[xg_base + (size_t)((n + 6 < N_) ? n + 6 : N_ - 1) * xg_nstride];
        step(n + 3, p3);
        p3 = xg[xg_base + (size_t)((n + 7 < N_) ? n + 7 : N_ - 1) * xg_nstride];
    }
}

extern "C" void kernel_launch(void* const* d_in, const int* in_sizes, int n_in,
                              void* d_out, int out_size, void* d_ws, size_t ws_size,
                              hipStream_t stream)
{
    const float* x   = (const float*)d_in[0];
    const float* Wih = (const float*)d_in[1];
    const float* Whh = (const float*)d_in[2];
    const float* bih = (const float*)d_in[3];
    const float* bhh = (const float*)d_in[4];
    float* out = (float*)d_out;
    float* xg  = (float*)d_ws;   // 65536 * 256 * 4 B = 64 MiB scratch

    dim3 ggrid(4, 1024);   // (g-tiles, m-tiles)
    gemm_xg_kernel<<<ggrid, 256, 0, stream>>>(x, Wih, bih, bhh, xg);
    lstm_scan_kernel<<<64, 512, 0, stream>>>(xg, Whh, out);
}